// Round 2
// baseline (609.094 us; speedup 1.0000x reference)
//
#include <hip/hip_runtime.h>
#include <cstdint>
#include <cstddef>

typedef unsigned short u16;
typedef __bf16 bf16x8 __attribute__((ext_vector_type(8)));
typedef float f32x4 __attribute__((ext_vector_type(4)));

#define SCALE_Q 0.125f

static __device__ __forceinline__ float b2f(u16 u){ return __uint_as_float(((unsigned)u)<<16); }
static __device__ __forceinline__ u16 f2b(float f){
  unsigned u = __float_as_uint(f);
  return (u16)((u + 0x7fffu + ((u>>16)&1u)) >> 16);
}
// async global->LDS, 16 B per lane; LDS dest is wave-uniform base + lane*16
static __device__ __forceinline__ void gload_lds16(const void* g, void* l){
  auto gp = reinterpret_cast<__attribute__((address_space(1))) uint32_t*>(reinterpret_cast<uintptr_t>(g));
  auto lp = reinterpret_cast<__attribute__((address_space(3))) uint32_t*>(reinterpret_cast<uintptr_t>(l));
  __builtin_amdgcn_global_load_lds(gp, lp, 16, 0, 0);
}

// ---------------- weight transpose f32 -> bf16, 32x32 tiles ----------------
__global__ __launch_bounds__(256) void transpose_f2b(const float* __restrict__ in, u16* __restrict__ out,
                                                     int R, int C){
  __shared__ float tile[32][33];
  int tx = threadIdx.x, ty = threadIdx.y;
  int c0 = blockIdx.x*32, r0 = blockIdx.y*32;
  #pragma unroll
  for (int i=0;i<4;i++) tile[ty+i*8][tx] = in[(size_t)(r0+ty+i*8)*C + c0+tx];
  __syncthreads();
  #pragma unroll
  for (int i=0;i<4;i++) out[(size_t)(c0+ty+i*8)*R + r0+tx] = f2b(tile[tx][ty+i*8]);
}

// ---------------- bf16 raw transpose (for V), batched over z ----------------
__global__ __launch_bounds__(256) void transpose_bf16(const u16* __restrict__ in, u16* __restrict__ out,
                                                      int R, int C){
  __shared__ u16 tile[32][33];
  size_t zoff = (size_t)blockIdx.z * R * C;
  const u16* ip = in + zoff;
  u16* op = out + zoff;
  int tx = threadIdx.x, ty = threadIdx.y;
  int c0 = blockIdx.x*32, r0 = blockIdx.y*32;
  #pragma unroll
  for (int i=0;i<4;i++) tile[ty+i*8][tx] = ip[(size_t)(r0+ty+i*8)*C + c0+tx];
  __syncthreads();
  #pragma unroll
  for (int i=0;i<4;i++) op[(size_t)(c0+ty+i*8)*R + r0+tx] = tile[tx][ty+i*8];
}

// ---------------- router logits: one wave per row (f32) ----------------
__global__ __launch_bounds__(256) void router_kernel(const float* __restrict__ x, const float* __restrict__ wr,
                                                     float* __restrict__ logits){
  int row = blockIdx.x*4 + (threadIdx.x>>6);
  int l = threadIdx.x & 63;
  const float4* xr = (const float4*)(x + (size_t)row*1024) + l;
  const float4* wp = (const float4*)wr + l;
  float acc = 0.f;
  #pragma unroll
  for (int c=0;c<4;c++){
    float4 xv = xr[c*64];
    float4 wv = wp[c*64];
    acc += xv.x*wv.x + xv.y*wv.y + xv.z*wv.z + xv.w*wv.w;
  }
  #pragma unroll
  for (int m=1;m<64;m<<=1) acc += __shfl_xor(acc, m, 64);
  if (l==0) logits[row] = acc;
}

// ---------------- exact top-K (radix select) + softmax weights + inverse map ----------------
static __device__ __forceinline__ unsigned mapkey(float f){
  unsigned u = __float_as_uint(f);
  return (u & 0x80000000u) ? ~u : (u | 0x80000000u);   // monotone: bigger float -> bigger key
}
static __device__ unsigned blk_scan_excl(unsigned cnt, unsigned* swav){
  int t = threadIdx.x; int l = t&63, w = t>>6;
  unsigned v = cnt;
  #pragma unroll
  for (int off=1; off<64; off<<=1){
    unsigned n = __shfl_up(v, off, 64);
    if (l >= off) v += n;
  }
  __syncthreads();
  if (l==63) swav[w] = v;
  __syncthreads();
  if (t==0){ unsigned c=0; for (int i=0;i<16;i++){ unsigned tmp=swav[i]; swav[i]=c; c+=tmp; } }
  __syncthreads();
  return swav[w] + v - cnt;
}
__global__ __launch_bounds__(1024) void topk_kernel(const float* __restrict__ logits,
        int* __restrict__ sel, float* __restrict__ rw, int* __restrict__ inv){
  int b = blockIdx.x, t = threadIdx.x;
  int l = t&63, w = t>>6;
  __shared__ float vals[4096];
  __shared__ unsigned hist[256];
  __shared__ unsigned swav[16];
  __shared__ float fwav[16];
  __shared__ unsigned sh_prefix, sh_remaining;
  const float* lgp = logits + b*4096;
  for (int i=t;i<4096;i+=1024) vals[i]=lgp[i];
  if (t==0){ sh_prefix=0u; sh_remaining=2048u; }
  __syncthreads();
  for (int level=0; level<4; level++){
    int shift = 24 - level*8;
    if (t<256) hist[t]=0u;
    __syncthreads();
    unsigned pfx = sh_prefix;
    for (int i=t;i<4096;i+=1024){
      unsigned key = mapkey(vals[i]);
      if (level==0 || (key >> (shift+8)) == pfx)
        atomicAdd(&hist[(key>>shift)&255u], 1u);
    }
    __syncthreads();
    if (t==0){
      unsigned rem = sh_remaining, cum=0u; unsigned bsel=0u;
      for (int bin=255; bin>=0; bin--){
        unsigned hc = hist[bin];
        if (cum + hc >= rem){ bsel=(unsigned)bin; break; }
        cum += hc;
      }
      sh_remaining = rem - cum;
      sh_prefix = (pfx<<8) | bsel;
    }
    __syncthreads();
  }
  unsigned T = sh_prefix;       // key of the 2048-th largest
  unsigned req = sh_remaining;  // how many ==T to take (lowest index first, matches top_k)
  int i0 = t*4;
  unsigned gt_[4], eq_[4], fl_[4]; float v_[4];
  #pragma unroll
  for (int j=0;j<4;j++){
    v_[j] = vals[i0+j];
    unsigned key = mapkey(v_[j]);
    gt_[j] = key > T ? 1u:0u;
    eq_[j] = key == T ? 1u:0u;
  }
  unsigned eqbase = blk_scan_excl(eq_[0]+eq_[1]+eq_[2]+eq_[3], swav);
  unsigned er = eqbase;
  #pragma unroll
  for (int j=0;j<4;j++){ fl_[j] = gt_[j] | (eq_[j] & (er < req ? 1u:0u)); er += eq_[j]; }
  unsigned pbase = blk_scan_excl(fl_[0]+fl_[1]+fl_[2]+fl_[3], swav);
  unsigned p = pbase;
  #pragma unroll
  for (int j=0;j<4;j++){
    int i = i0+j;
    if (fl_[j]){ sel[b*2048+(int)p]=i; inv[b*4096+i]=(int)p; p++; }
    else inv[b*4096+i] = -1;
  }
  // softmax over selected logits (global max is always selected: it is top-1)
  float mx = fmaxf(fmaxf(v_[0],v_[1]), fmaxf(v_[2],v_[3]));
  #pragma unroll
  for (int m=1;m<64;m<<=1) mx = fmaxf(mx, __shfl_xor(mx,m,64));
  __syncthreads();
  if (l==0) fwav[w]=mx;
  __syncthreads();
  if (t==0){ float g=fwav[0]; for(int i=1;i<16;i++) g=fmaxf(g,fwav[i]); fwav[0]=g; }
  __syncthreads();
  float gm = fwav[0];
  float zz = 0.f;
  #pragma unroll
  for (int j=0;j<4;j++) if (fl_[j]) zz += expf(v_[j]-gm);
  #pragma unroll
  for (int m=1;m<64;m<<=1) zz += __shfl_xor(zz,m,64);
  __syncthreads();
  if (l==0) fwav[w]=zz;
  __syncthreads();
  if (t==0){ float s=0.f; for(int i=0;i<16;i++) s+=fwav[i]; fwav[0]=s; }
  __syncthreads();
  float Z = fwav[0];
  unsigned p2 = pbase;
  #pragma unroll
  for (int j=0;j<4;j++) if (fl_[j]){ rw[b*2048+(int)p2] = expf(v_[j]-gm)/Z; p2++; }
}

// ---------------- (gathered) RMSNorm f32 -> bf16; optionally emits raw f32 gathered copy ----------------
__global__ __launch_bounds__(256) void rmsnorm_kernel(const float* __restrict__ xin,
        const float* __restrict__ gamma, const int* __restrict__ sel,
        u16* __restrict__ xn, float* __restrict__ xf){
  int r = blockIdx.x;
  int src = r;
  if (sel) src = (r>>11)*4096 + sel[r];
  const float* row = xin + (size_t)src*1024;
  int t = threadIdx.x, l = t&63, w = t>>6;
  int d0 = t*4;
  float4 xv = *(const float4*)(row + d0);
  float ss = xv.x*xv.x + xv.y*xv.y + xv.z*xv.z + xv.w*xv.w;
  #pragma unroll
  for (int m=1;m<64;m<<=1) ss += __shfl_xor(ss,m,64);
  __shared__ float red[4];
  if (l==0) red[w]=ss;
  __syncthreads();
  float tot = red[0]+red[1]+red[2]+red[3];
  float rms = rsqrtf(tot*(1.f/1024.f) + 1e-5f);
  float4 gv = *(const float4*)(gamma + d0);
  u16 o0=f2b(xv.x*rms*gv.x), o1=f2b(xv.y*rms*gv.y), o2=f2b(xv.z*rms*gv.z), o3=f2b(xv.w*rms*gv.w);
  uint2 ov; ov.x = (unsigned)o0 | ((unsigned)o1<<16); ov.y = (unsigned)o2 | ((unsigned)o3<<16);
  *(uint2*)(xn + (size_t)r*1024 + d0) = ov;
  if (xf) *(float4*)(xf + (size_t)r*1024 + d0) = xv;
}

// ---------------- m97-style GEMM: C = A(MxK,bf16) * Bt(NxK,bf16)^T (+f32 resid), f32 acc ----------------
template<typename OT>
__global__ __launch_bounds__(256,2) void gemm_bt(const u16* __restrict__ A, const u16* __restrict__ Bt,
        OT* __restrict__ C, const float* __restrict__ resid, int M, int N, int Kd){
  __shared__ u16 As[128*32];
  __shared__ u16 Bs[128*32];
  int t = threadIdx.x, w = t>>6, l = t&63, lg = l>>4, ln = l&15;
  int m0 = blockIdx.y*128, n0 = blockIdx.x*128;
  int wm = (w&1)*64, wn = (w>>1)*64;
  f32x4 acc[4][4] = {};
  for (int k0=0; k0<Kd; k0+=32){
    __syncthreads();
    #pragma unroll
    for (int c=0;c<2;c++){
      int off = t*16 + c*4096;          // byte offset in 8 KB tile
      int row = off>>6, ku = (off&63)>>1;
      gload_lds16(A  + (size_t)(m0+row)*Kd + k0 + ku, &As[w*512 + c*2048]);
      gload_lds16(Bt + (size_t)(n0+row)*Kd + k0 + ku, &Bs[w*512 + c*2048]);
    }
    __syncthreads();
    bf16x8 af[4], bfv[4];
    #pragma unroll
    for (int i=0;i<4;i++){
      af[i]  = *(const bf16x8*)&As[(wm+i*16+ln)*32 + lg*8];
      bfv[i] = *(const bf16x8*)&Bs[(wn+i*16+ln)*32 + lg*8];
    }
    #pragma unroll
    for (int mi=0;mi<4;mi++)
      #pragma unroll
      for (int ni=0;ni<4;ni++)
        acc[mi][ni] = __builtin_amdgcn_mfma_f32_16x16x32_bf16(af[mi], bfv[ni], acc[mi][ni], 0,0,0);
  }
  #pragma unroll
  for (int mi=0;mi<4;mi++){
    #pragma unroll
    for (int ni=0;ni<4;ni++){
      #pragma unroll
      for (int r=0;r<4;r++){
        int row = m0+wm+mi*16+lg*4+r;
        int col = n0+wn+ni*16+ln;
        float v = acc[mi][ni][r];
        if (resid) v += resid[(size_t)row*N + col];
        if constexpr (sizeof(OT)==2) C[(size_t)row*N + col] = f2b(v);
        else                          C[(size_t)row*N + col] = v;
      }
    }
  }
}

// ---------------- RoPE + QKV unpack (q scaled by 1/sqrt(HD)); fcos/fsin f32 ----------------
__global__ __launch_bounds__(256) void rope_kernel(const u16* __restrict__ QKV,
        const float* __restrict__ fcos, const float* __restrict__ fsin,
        u16* __restrict__ q_r, u16* __restrict__ k_r, u16* __restrict__ v_r){
  int row = blockIdx.x;              // b*2048+tok
  int tok = row & 2047;
  int t = threadIdx.x;
  int d0 = t*4;
  int h = d0 >> 6, wd = d0 & 63, i0 = wd >> 1;
  const u16* base = QKV + (size_t)row*3072;
  size_t ob = (((size_t)(row>>11)*16 + h)*2048 + (size_t)tok)*64 + wd;
  float c0 = fcos[tok*32+i0],   s0 = fsin[tok*32+i0];
  float c1 = fcos[tok*32+i0+1], s1 = fsin[tok*32+i0+1];
  const u16* qp = base + d0;
  float x0=b2f(qp[0]), x1=b2f(qp[1]), x2=b2f(qp[2]), x3=b2f(qp[3]);
  q_r[ob]   = f2b((x0*c0-x1*s0)*SCALE_Q);
  q_r[ob+1] = f2b((x0*s0+x1*c0)*SCALE_Q);
  q_r[ob+2] = f2b((x2*c1-x3*s1)*SCALE_Q);
  q_r[ob+3] = f2b((x2*s1+x3*c1)*SCALE_Q);
  const u16* kp = base + 1024 + d0;
  x0=b2f(kp[0]); x1=b2f(kp[1]); x2=b2f(kp[2]); x3=b2f(kp[3]);
  k_r[ob]   = f2b(x0*c0-x1*s0);
  k_r[ob+1] = f2b(x0*s0+x1*c0);
  k_r[ob+2] = f2b(x2*c1-x3*s1);
  k_r[ob+3] = f2b(x2*s1+x3*c1);
  const u16* vp = base + 2048 + d0;
  v_r[ob]=vp[0]; v_r[ob+1]=vp[1]; v_r[ob+2]=vp[2]; v_r[ob+3]=vp[3];
}

// ---------------- flash attention fwd, causal, HD=64; 64 q-rows/block, 64 kv/tile ----------------
__global__ __launch_bounds__(256,2) void flash_kernel(const u16* __restrict__ q_r,
        const u16* __restrict__ k_r, const u16* __restrict__ v_t, u16* __restrict__ o){
  const int S = 2048;
  int qt = blockIdx.x, bh = blockIdx.y;
  int b = bh>>4, h = bh&15;
  int t = threadIdx.x, w = t>>6, l = t&63, lg = l>>4, ln = l&15;
  __shared__ u16 Ks[64*72];      // [token][dim], stride 72 (16B-aligned rows)
  __shared__ u16 Vs[64*72];      // [dim][token]
  __shared__ u16 Ps[4][16*72];   // per-wave P round-trip
  const u16* qb = q_r + (size_t)bh*S*64;
  const u16* kb = k_r + (size_t)bh*S*64;
  const u16* vb = v_t + (size_t)bh*64*S;
  int q0 = qt*64;
  bf16x8 qf0 = *(const bf16x8*)(qb + (size_t)(q0 + w*16 + ln)*64 + lg*8);
  bf16x8 qf1 = *(const bf16x8*)(qb + (size_t)(q0 + w*16 + ln)*64 + 32 + lg*8);
  f32x4 oacc[4] = {};
  float mi_[4], li_[4];
  #pragma unroll
  for (int r=0;r<4;r++){ mi_[r]=-1e30f; li_[r]=0.f; }
  for (int kv=0; kv<=qt; kv++){
    int k0 = kv*64;
    __syncthreads();
    #pragma unroll
    for (int c=0;c<2;c++){
      int idx = c*256 + t;
      int rr = idx>>3, p8 = (idx&7)*8;
      *(bf16x8*)&Ks[rr*72 + p8] = *(const bf16x8*)(kb + (size_t)(k0+rr)*64 + p8);
      *(bf16x8*)&Vs[rr*72 + p8] = *(const bf16x8*)(vb + (size_t)rr*S + k0 + p8);
    }
    __syncthreads();
    f32x4 sv[4];
    #pragma unroll
    for (int ni=0;ni<4;ni++){
      bf16x8 kf0 = *(const bf16x8*)&Ks[(ni*16+ln)*72 + lg*8];
      bf16x8 kf1 = *(const bf16x8*)&Ks[(ni*16+ln)*72 + 32 + lg*8];
      f32x4 z = {};
      z = __builtin_amdgcn_mfma_f32_16x16x32_bf16(qf0, kf0, z, 0,0,0);
      z = __builtin_amdgcn_mfma_f32_16x16x32_bf16(qf1, kf1, z, 0,0,0);
      sv[ni] = z;
    }
    bool diag = (kv==qt);
    float pm[4][4], alpha[4];
    #pragma unroll
    for (int r=0;r<4;r++){
      int qrow = q0 + w*16 + lg*4 + r;
      float rm = -1e30f;
      #pragma unroll
      for (int ni=0;ni<4;ni++){
        float xs = sv[ni][r];
        if (diag && (k0+ni*16+ln) > qrow) xs = -1e30f;
        sv[ni][r] = xs;
        rm = fmaxf(rm, xs);
      }
      #pragma unroll
      for (int m=1;m<16;m<<=1) rm = fmaxf(rm, __shfl_xor(rm,m,64));
      float mn = fmaxf(mi_[r], rm);
      alpha[r] = __expf(mi_[r] - mn);
      float ls = 0.f;
      #pragma unroll
      for (int ni=0;ni<4;ni++){ float pp = __expf(sv[ni][r]-mn); pm[ni][r]=pp; ls+=pp; }
      #pragma unroll
      for (int m=1;m<16;m<<=1) ls += __shfl_xor(ls,m,64);
      li_[r] = li_[r]*alpha[r] + ls;
      mi_[r] = mn;
    }
    #pragma unroll
    for (int ni=0;ni<4;ni++)
      #pragma unroll
      for (int r=0;r<4;r++)
        Ps[w][(lg*4+r)*72 + ni*16 + ln] = f2b(pm[ni][r]);
    __syncthreads();   // C-layout -> A-layout round trip
    bf16x8 pf0 = *(const bf16x8*)&Ps[w][ln*72 + lg*8];
    bf16x8 pf1 = *(const bf16x8*)&Ps[w][ln*72 + 32 + lg*8];
    #pragma unroll
    for (int dt=0; dt<4; dt++){
      bf16x8 vf0 = *(const bf16x8*)&Vs[(dt*16+ln)*72 + lg*8];
      bf16x8 vf1 = *(const bf16x8*)&Vs[(dt*16+ln)*72 + 32 + lg*8];
      f32x4 oo = oacc[dt];
      #pragma unroll
      for (int r=0;r<4;r++) oo[r] *= alpha[r];
      oo = __builtin_amdgcn_mfma_f32_16x16x32_bf16(pf0, vf0, oo, 0,0,0);
      oo = __builtin_amdgcn_mfma_f32_16x16x32_bf16(pf1, vf1, oo, 0,0,0);
      oacc[dt] = oo;
    }
  }
  #pragma unroll
  for (int dt=0; dt<4; dt++){
    #pragma unroll
    for (int r=0;r<4;r++){
      int tok = q0 + w*16 + lg*4 + r;
      int dim = dt*16 + ln;
      o[((size_t)(b*S+tok))*1024 + h*64 + dim] = f2b(oacc[dt][r] / li_[r]);
    }
  }
}

// ---------------- SwiGLU: g = silu(a13[:, :4096]) * a13[:, 4096:]  (bf16) ----------------
__global__ __launch_bounds__(256) void silu_kernel(const u16* __restrict__ a13, u16* __restrict__ g){
  size_t idx = ((size_t)blockIdx.x*256 + threadIdx.x)*8;
  size_t r = idx >> 12;
  size_t c = idx & 4095;
  const u16* p1 = a13 + r*8192 + c;
  const u16* p3 = p1 + 4096;
  bf16x8 x1 = *(const bf16x8*)p1;
  bf16x8 x3 = *(const bf16x8*)p3;
  u16 outv[8];
  #pragma unroll
  for (int i=0;i<8;i++){
    float a = (float)x1[i], b3 = (float)x3[i];
    float s = a / (1.f + __expf(-a));
    outv[i] = f2b(s*b3);
  }
  uint4 ov;
  ov.x = (unsigned)outv[0] | ((unsigned)outv[1]<<16);
  ov.y = (unsigned)outv[2] | ((unsigned)outv[3]<<16);
  ov.z = (unsigned)outv[4] | ((unsigned)outv[5]<<16);
  ov.w = (unsigned)outv[6] | ((unsigned)outv[7]<<16);
  *(uint4*)(g + idx) = ov;
}

// ---------------- out = x (+ rw * (h + y) on selected rows), f32 out ----------------
__global__ __launch_bounds__(256) void final_kernel(const float* __restrict__ x, const float* __restrict__ h,
        const u16* __restrict__ y, const int* __restrict__ inv, const float* __restrict__ rw,
        float* __restrict__ out){
  int row = blockIdx.x;
  int b = row>>12;
  int t = threadIdx.x, d0 = t*4;
  float4 xv = *(const float4*)(x + (size_t)row*1024 + d0);
  float4* op = (float4*)(out + (size_t)row*1024 + d0);
  int j = inv[row];
  if (j < 0){ *op = xv; return; }
  int fr = b*2048 + j;
  float wgt = rw[fr];
  float4 hv = *(const float4*)(h + (size_t)fr*1024 + d0);
  uint2 yv = *(const uint2*)(y + (size_t)fr*1024 + d0);
  float y0=b2f((u16)(yv.x&0xffffu)), y1=b2f((u16)(yv.x>>16)), y2=b2f((u16)(yv.y&0xffffu)), y3=b2f((u16)(yv.y>>16));
  float4 ov;
  ov.x = xv.x + wgt*(hv.x + y0);
  ov.y = xv.y + wgt*(hv.y + y1);
  ov.z = xv.z + wgt*(hv.z + y2);
  ov.w = xv.w + wgt*(hv.w + y3);
  *op = ov;
}

extern "C" void kernel_launch(void* const* d_in, const int* in_sizes, int n_in,
                              void* d_out, int out_size, void* d_ws, size_t ws_size,
                              hipStream_t stream) {
  (void)in_sizes; (void)n_in; (void)out_size; (void)ws_size;
  const float* x     = (const float*)d_in[0];
  // d_in[1] = mask (tril, static) -- unused, causality computed by index
  const float* fcos  = (const float*)d_in[2];
  const float* fsin  = (const float*)d_in[3];
  const float* wr    = (const float*)d_in[4];
  const float* anorm = (const float*)d_in[5];
  const float* wq    = (const float*)d_in[6];
  const float* wk    = (const float*)d_in[7];
  const float* wv    = (const float*)d_in[8];
  const float* wo    = (const float*)d_in[9];
  const float* fnorm = (const float*)d_in[10];
  const float* w1    = (const float*)d_in[11];
  const float* w2    = (const float*)d_in[12];
  const float* w3    = (const float*)d_in[13];
  float* out = (float*)d_out;

  char* W = (char*)d_ws;
  const size_t MB = 1024*1024;
  u16* WqkvT = (u16*)(W + 0);          // 6 MB  (3072 x 1024 bf16)
  u16* WoT   = (u16*)(W + 6*MB);       // 2 MB
  u16* W13T  = (u16*)(W + 8*MB);       // 16 MB (8192 x 1024)
  u16* W2T   = (u16*)(W + 24*MB);      // 8 MB  (1024 x 4096)
  float* xf  = (float*)(W + 32*MB);    // 16 MB f32 gathered x (dead after o-proj)
  u16* xn    = (u16*)(W + 48*MB);      // 8 MB  (dead after QKV gemm)
  u16* QKV   = (u16*)(W + 56*MB);      // 24 MB (dead after rope)
  u16* q_r   = (u16*)(W + 80*MB);      // 8 MB  (dead after flash)
  u16* k_r   = (u16*)(W + 88*MB);      // 8 MB
  u16* v_r   = (u16*)(W + 96*MB);      // 8 MB  (dead after v-transpose)
  u16* v_t   = (u16*)(W + 104*MB);     // 8 MB  (dead after flash)
  u16* attno = (u16*)(W + 112*MB);     // 8 MB  (dead after o-proj)
  float* hbuf= (float*)(W + 120*MB);   // 16 MB f32 (live till final)
  u16* hn    = (u16*)(W + 136*MB);     // 8 MB  (dead after FFN13)
  u16* a13   = (u16*)(W + 48*MB);      // 64 MB overlay (48..112MB, all dead by then)
  u16* g     = (u16*)(W + 144*MB);     // 32 MB
  u16* ybuf  = (u16*)(W + 32*MB);      // 8 MB overlay on dead xf
  float* logits = (float*)(W + 176*MB);            // 32 KB
  int*   sel    = (int*)(W + 176*MB + 64*1024);    // 16 KB
  float* rw     = (float*)(W + 176*MB + 96*1024);  // 16 KB
  int*   inv    = (int*)(W + 176*MB + 128*1024);   // 32 KB

  dim3 tb(32,8);
  // weight transposes + f32->bf16 (Bt layout for gemm_bt)
  transpose_f2b<<<dim3(32,32,1),  tb, 0, stream>>>(wq, WqkvT,                1024, 1024);
  transpose_f2b<<<dim3(32,32,1),  tb, 0, stream>>>(wk, WqkvT + 1024*1024,    1024, 1024);
  transpose_f2b<<<dim3(32,32,1),  tb, 0, stream>>>(wv, WqkvT + 2*1024*1024,  1024, 1024);
  transpose_f2b<<<dim3(32,32,1),  tb, 0, stream>>>(wo, WoT,                  1024, 1024);
  transpose_f2b<<<dim3(128,32,1), tb, 0, stream>>>(w1, W13T,                 1024, 4096);
  transpose_f2b<<<dim3(128,32,1), tb, 0, stream>>>(w3, W13T + 4096*1024,     1024, 4096);
  transpose_f2b<<<dim3(32,128,1), tb, 0, stream>>>(w2, W2T,                  4096, 1024);

  router_kernel<<<2048, 256, 0, stream>>>(x, wr, logits);
  topk_kernel<<<2, 1024, 0, stream>>>(logits, sel, rw, inv);
  rmsnorm_kernel<<<4096, 256, 0, stream>>>(x, anorm, sel, xn, xf);
  gemm_bt<u16><<<dim3(24,32), 256, 0, stream>>>(xn, WqkvT, QKV, nullptr, 4096, 3072, 1024);
  rope_kernel<<<4096, 256, 0, stream>>>(QKV, fcos, fsin, q_r, k_r, v_r);
  transpose_bf16<<<dim3(2,64,32), tb, 0, stream>>>(v_r, v_t, 2048, 64);
  flash_kernel<<<dim3(32,32), 256, 0, stream>>>(q_r, k_r, v_t, attno);
  gemm_bt<float><<<dim3(8,32), 256, 0, stream>>>(attno, WoT, hbuf, xf, 4096, 1024, 1024);
  rmsnorm_kernel<<<4096, 256, 0, stream>>>(hbuf, fnorm, nullptr, hn, nullptr);
  gemm_bt<u16><<<dim3(64,32), 256, 0, stream>>>(hn, W13T, a13, nullptr, 4096, 8192, 1024);
  silu_kernel<<<8192, 256, 0, stream>>>(a13, g);
  gemm_bt<u16><<<dim3(8,32), 256, 0, stream>>>(g, W2T, ybuf, nullptr, 4096, 1024, 4096);
  final_kernel<<<8192, 256, 0, stream>>>(x, hbuf, ybuf, inv, rw, out);
}

// Round 3
// 555.066 us; speedup vs baseline: 1.0973x; 1.0973x over previous
//
#include <hip/hip_runtime.h>
#include <cstdint>
#include <cstddef>

typedef unsigned short u16;
typedef __bf16 bf16x8 __attribute__((ext_vector_type(8)));
typedef float f32x4 __attribute__((ext_vector_type(4)));

// q is pre-scaled by 1/sqrt(64) * log2(e) so flash softmax runs in exp2 domain
#define SCALE_Q_LOG2E 0.18033688011112042f

static __device__ __forceinline__ float b2f(u16 u){ return __uint_as_float(((unsigned)u)<<16); }
static __device__ __forceinline__ u16 f2b(float f){
  unsigned u = __float_as_uint(f);
  return (u16)((u + 0x7fffu + ((u>>16)&1u)) >> 16);
}
// async global->LDS, 16 B per lane; LDS dest is wave-uniform base + lane*16
static __device__ __forceinline__ void gload_lds16(const void* g, void* l){
  auto gp = reinterpret_cast<__attribute__((address_space(1))) uint32_t*>(reinterpret_cast<uintptr_t>(g));
  auto lp = reinterpret_cast<__attribute__((address_space(3))) uint32_t*>(reinterpret_cast<uintptr_t>(l));
  __builtin_amdgcn_global_load_lds(gp, lp, 16, 0, 0);
}

// ---------------- weight transpose f32 -> bf16, 32x32 tiles ----------------
__global__ __launch_bounds__(256) void transpose_f2b(const float* __restrict__ in, u16* __restrict__ out,
                                                     int R, int C){
  __shared__ float tile[32][33];
  int tx = threadIdx.x, ty = threadIdx.y;
  int c0 = blockIdx.x*32, r0 = blockIdx.y*32;
  #pragma unroll
  for (int i=0;i<4;i++) tile[ty+i*8][tx] = in[(size_t)(r0+ty+i*8)*C + c0+tx];
  __syncthreads();
  #pragma unroll
  for (int i=0;i<4;i++) out[(size_t)(c0+ty+i*8)*R + r0+tx] = f2b(tile[tx][ty+i*8]);
}

// ---------------- bf16 raw transpose (for V), batched over z ----------------
__global__ __launch_bounds__(256) void transpose_bf16(const u16* __restrict__ in, u16* __restrict__ out,
                                                      int R, int C){
  __shared__ u16 tile[32][33];
  size_t zoff = (size_t)blockIdx.z * R * C;
  const u16* ip = in + zoff;
  u16* op = out + zoff;
  int tx = threadIdx.x, ty = threadIdx.y;
  int c0 = blockIdx.x*32, r0 = blockIdx.y*32;
  #pragma unroll
  for (int i=0;i<4;i++) tile[ty+i*8][tx] = ip[(size_t)(r0+ty+i*8)*C + c0+tx];
  __syncthreads();
  #pragma unroll
  for (int i=0;i<4;i++) op[(size_t)(c0+ty+i*8)*R + r0+tx] = tile[tx][ty+i*8];
}

// ---------------- router logits: one wave per row (f32) ----------------
__global__ __launch_bounds__(256) void router_kernel(const float* __restrict__ x, const float* __restrict__ wr,
                                                     float* __restrict__ logits){
  int row = blockIdx.x*4 + (threadIdx.x>>6);
  int l = threadIdx.x & 63;
  const float4* xr = (const float4*)(x + (size_t)row*1024) + l;
  const float4* wp = (const float4*)wr + l;
  float acc = 0.f;
  #pragma unroll
  for (int c=0;c<4;c++){
    float4 xv = xr[c*64];
    float4 wv = wp[c*64];
    acc += xv.x*wv.x + xv.y*wv.y + xv.z*wv.z + xv.w*wv.w;
  }
  #pragma unroll
  for (int m=1;m<64;m<<=1) acc += __shfl_xor(acc, m, 64);
  if (l==0) logits[row] = acc;
}

// ---------------- exact top-K (radix select) + softmax weights + inverse map ----------------
static __device__ __forceinline__ unsigned mapkey(float f){
  unsigned u = __float_as_uint(f);
  return (u & 0x80000000u) ? ~u : (u | 0x80000000u);   // monotone: bigger float -> bigger key
}
static __device__ unsigned blk_scan_excl(unsigned cnt, unsigned* swav){
  int t = threadIdx.x; int l = t&63, w = t>>6;
  unsigned v = cnt;
  #pragma unroll
  for (int off=1; off<64; off<<=1){
    unsigned n = __shfl_up(v, off, 64);
    if (l >= off) v += n;
  }
  __syncthreads();
  if (l==63) swav[w] = v;
  __syncthreads();
  if (t==0){ unsigned c=0; for (int i=0;i<16;i++){ unsigned tmp=swav[i]; swav[i]=c; c+=tmp; } }
  __syncthreads();
  return swav[w] + v - cnt;
}
__global__ __launch_bounds__(1024) void topk_kernel(const float* __restrict__ logits,
        int* __restrict__ sel, float* __restrict__ rw, int* __restrict__ inv){
  int b = blockIdx.x, t = threadIdx.x;
  int l = t&63, w = t>>6;
  __shared__ float vals[4096];
  __shared__ unsigned hist[256];
  __shared__ unsigned swav[16];
  __shared__ float fwav[16];
  __shared__ unsigned sh_prefix, sh_remaining;
  const float* lgp = logits + b*4096;
  for (int i=t;i<4096;i+=1024) vals[i]=lgp[i];
  if (t==0){ sh_prefix=0u; sh_remaining=2048u; }
  __syncthreads();
  for (int level=0; level<4; level++){
    int shift = 24 - level*8;
    if (t<256) hist[t]=0u;
    __syncthreads();
    unsigned pfx = sh_prefix;
    for (int i=t;i<4096;i+=1024){
      unsigned key = mapkey(vals[i]);
      if (level==0 || (key >> (shift+8)) == pfx)
        atomicAdd(&hist[(key>>shift)&255u], 1u);
    }
    __syncthreads();
    if (t==0){
      unsigned rem = sh_remaining, cum=0u; unsigned bsel=0u;
      for (int bin=255; bin>=0; bin--){
        unsigned hc = hist[bin];
        if (cum + hc >= rem){ bsel=(unsigned)bin; break; }
        cum += hc;
      }
      sh_remaining = rem - cum;
      sh_prefix = (pfx<<8) | bsel;
    }
    __syncthreads();
  }
  unsigned T = sh_prefix;       // key of the 2048-th largest
  unsigned req = sh_remaining;  // how many ==T to take (lowest index first, matches top_k)
  int i0 = t*4;
  unsigned gt_[4], eq_[4], fl_[4]; float v_[4];
  #pragma unroll
  for (int j=0;j<4;j++){
    v_[j] = vals[i0+j];
    unsigned key = mapkey(v_[j]);
    gt_[j] = key > T ? 1u:0u;
    eq_[j] = key == T ? 1u:0u;
  }
  unsigned eqbase = blk_scan_excl(eq_[0]+eq_[1]+eq_[2]+eq_[3], swav);
  unsigned er = eqbase;
  #pragma unroll
  for (int j=0;j<4;j++){ fl_[j] = gt_[j] | (eq_[j] & (er < req ? 1u:0u)); er += eq_[j]; }
  unsigned pbase = blk_scan_excl(fl_[0]+fl_[1]+fl_[2]+fl_[3], swav);
  unsigned p = pbase;
  #pragma unroll
  for (int j=0;j<4;j++){
    int i = i0+j;
    if (fl_[j]){ sel[b*2048+(int)p]=i; inv[b*4096+i]=(int)p; p++; }
    else inv[b*4096+i] = -1;
  }
  // softmax over selected logits (global max is always selected: it is top-1)
  float mx = fmaxf(fmaxf(v_[0],v_[1]), fmaxf(v_[2],v_[3]));
  #pragma unroll
  for (int m=1;m<64;m<<=1) mx = fmaxf(mx, __shfl_xor(mx,m,64));
  __syncthreads();
  if (l==0) fwav[w]=mx;
  __syncthreads();
  if (t==0){ float g=fwav[0]; for(int i=1;i<16;i++) g=fmaxf(g,fwav[i]); fwav[0]=g; }
  __syncthreads();
  float gm = fwav[0];
  float zz = 0.f;
  #pragma unroll
  for (int j=0;j<4;j++) if (fl_[j]) zz += expf(v_[j]-gm);
  #pragma unroll
  for (int m=1;m<64;m<<=1) zz += __shfl_xor(zz,m,64);
  __syncthreads();
  if (l==0) fwav[w]=zz;
  __syncthreads();
  if (t==0){ float s=0.f; for(int i=0;i<16;i++) s+=fwav[i]; fwav[0]=s; }
  __syncthreads();
  float Z = fwav[0];
  unsigned p2 = pbase;
  #pragma unroll
  for (int j=0;j<4;j++) if (fl_[j]){ rw[b*2048+(int)p2] = expf(v_[j]-gm)/Z; p2++; }
}

// ---------------- (gathered) RMSNorm f32 -> bf16; optionally emits raw f32 gathered copy ----------------
__global__ __launch_bounds__(256) void rmsnorm_kernel(const float* __restrict__ xin,
        const float* __restrict__ gamma, const int* __restrict__ sel,
        u16* __restrict__ xn, float* __restrict__ xf){
  int r = blockIdx.x;
  int src = r;
  if (sel) src = (r>>11)*4096 + sel[r];
  const float* row = xin + (size_t)src*1024;
  int t = threadIdx.x, l = t&63, w = t>>6;
  int d0 = t*4;
  float4 xv = *(const float4*)(row + d0);
  float ss = xv.x*xv.x + xv.y*xv.y + xv.z*xv.z + xv.w*xv.w;
  #pragma unroll
  for (int m=1;m<64;m<<=1) ss += __shfl_xor(ss,m,64);
  __shared__ float red[4];
  if (l==0) red[w]=ss;
  __syncthreads();
  float tot = red[0]+red[1]+red[2]+red[3];
  float rms = rsqrtf(tot*(1.f/1024.f) + 1e-5f);
  float4 gv = *(const float4*)(gamma + d0);
  u16 o0=f2b(xv.x*rms*gv.x), o1=f2b(xv.y*rms*gv.y), o2=f2b(xv.z*rms*gv.z), o3=f2b(xv.w*rms*gv.w);
  uint2 ov; ov.x = (unsigned)o0 | ((unsigned)o1<<16); ov.y = (unsigned)o2 | ((unsigned)o3<<16);
  *(uint2*)(xn + (size_t)r*1024 + d0) = ov;
  if (xf) *(float4*)(xf + (size_t)r*1024 + d0) = xv;
}

// ---------------- m97-style GEMM: C = A(128-tile) * Bt(BN-tile)^T (+f32 resid) ----------------
template<int BN, typename OT>
__global__ __launch_bounds__(256,2) void gemm_bt(const u16* __restrict__ A, const u16* __restrict__ Bt,
        OT* __restrict__ C, const float* __restrict__ resid, int M, int N, int Kd){
  __shared__ u16 As[128*32];
  __shared__ u16 Bs[BN*32];
  constexpr int NF = BN/32;         // n-frags per wave (4 for BN=128, 2 for BN=64)
  int t = threadIdx.x, w = t>>6, l = t&63, lg = l>>4, ln = l&15;
  int m0 = blockIdx.y*128, n0 = blockIdx.x*BN;
  int wm = (w&1)*64, wn = (w>>1)*(BN/2);
  f32x4 acc[4][NF] = {};
  for (int k0=0; k0<Kd; k0+=32){
    __syncthreads();
    #pragma unroll
    for (int c=0;c<2;c++){
      int off = t*16 + c*4096;          // byte offset in 8 KB tile
      int row = off>>6, ku = (off&63)>>1;
      gload_lds16(A  + (size_t)(m0+row)*Kd + k0 + ku, &As[w*512 + c*2048]);
    }
    #pragma unroll
    for (int c=0;c<BN/64;c++){
      int off = t*16 + c*4096;
      int row = off>>6, ku = (off&63)>>1;
      gload_lds16(Bt + (size_t)(n0+row)*Kd + k0 + ku, &Bs[w*512 + c*2048]);
    }
    __syncthreads();
    bf16x8 af[4], bfv[NF];
    #pragma unroll
    for (int i=0;i<4;i++) af[i]  = *(const bf16x8*)&As[(wm+i*16+ln)*32 + lg*8];
    #pragma unroll
    for (int i=0;i<NF;i++) bfv[i] = *(const bf16x8*)&Bs[(wn+i*16+ln)*32 + lg*8];
    #pragma unroll
    for (int mi=0;mi<4;mi++)
      #pragma unroll
      for (int ni=0;ni<NF;ni++)
        acc[mi][ni] = __builtin_amdgcn_mfma_f32_16x16x32_bf16(af[mi], bfv[ni], acc[mi][ni], 0,0,0);
  }
  #pragma unroll
  for (int mi=0;mi<4;mi++){
    #pragma unroll
    for (int ni=0;ni<NF;ni++){
      #pragma unroll
      for (int r=0;r<4;r++){
        int row = m0+wm+mi*16+lg*4+r;
        int col = n0+wn+ni*16+ln;
        float v = acc[mi][ni][r];
        if (resid) v += resid[(size_t)row*N + col];
        if constexpr (sizeof(OT)==2) C[(size_t)row*N + col] = f2b(v);
        else                          C[(size_t)row*N + col] = v;
      }
    }
  }
}

// ---------------- RoPE + QKV unpack (q scaled by 1/sqrt(HD)*log2e); fcos/fsin f32 ----------------
__global__ __launch_bounds__(256) void rope_kernel(const u16* __restrict__ QKV,
        const float* __restrict__ fcos, const float* __restrict__ fsin,
        u16* __restrict__ q_r, u16* __restrict__ k_r, u16* __restrict__ v_r){
  int row = blockIdx.x;              // b*2048+tok
  int tok = row & 2047;
  int t = threadIdx.x;
  int d0 = t*4;
  int h = d0 >> 6, wd = d0 & 63, i0 = wd >> 1;
  const u16* base = QKV + (size_t)row*3072;
  size_t ob = (((size_t)(row>>11)*16 + h)*2048 + (size_t)tok)*64 + wd;
  float c0 = fcos[tok*32+i0],   s0 = fsin[tok*32+i0];
  float c1 = fcos[tok*32+i0+1], s1 = fsin[tok*32+i0+1];
  const u16* qp = base + d0;
  float x0=b2f(qp[0]), x1=b2f(qp[1]), x2=b2f(qp[2]), x3=b2f(qp[3]);
  q_r[ob]   = f2b((x0*c0-x1*s0)*SCALE_Q_LOG2E);
  q_r[ob+1] = f2b((x0*s0+x1*c0)*SCALE_Q_LOG2E);
  q_r[ob+2] = f2b((x2*c1-x3*s1)*SCALE_Q_LOG2E);
  q_r[ob+3] = f2b((x2*s1+x3*c1)*SCALE_Q_LOG2E);
  const u16* kp = base + 1024 + d0;
  x0=b2f(kp[0]); x1=b2f(kp[1]); x2=b2f(kp[2]); x3=b2f(kp[3]);
  k_r[ob]   = f2b(x0*c0-x1*s0);
  k_r[ob+1] = f2b(x0*s0+x1*c0);
  k_r[ob+2] = f2b(x2*c1-x3*s1);
  k_r[ob+3] = f2b(x2*s1+x3*c1);
  const u16* vp = base + 2048 + d0;
  v_r[ob]=vp[0]; v_r[ob+1]=vp[1]; v_r[ob+2]=vp[2]; v_r[ob+3]=vp[3];
}

// ---------------- flash attention, causal, HD=64 ----------------
// Balanced: block p handles q-tiles {p, 31-p} -> exactly 33 KV iterations/block.
// Double-buffered K/V (1 barrier/iter), per-wave P round trip with no barrier,
// softmax in exp2 domain (q pre-scaled by log2e).
__global__ __launch_bounds__(256,2) void flash_kernel(const u16* __restrict__ q_r,
        const u16* __restrict__ k_r, const u16* __restrict__ v_t, u16* __restrict__ o){
  const int S = 2048;
  int pr = blockIdx.x, bh = blockIdx.y;
  int b = bh>>4, h = bh&15;
  int t = threadIdx.x, w = t>>6, l = t&63, lg = l>>4, ln = l&15;
  __shared__ u16 Ks[2][64*72];   // [token][dim], stride 72
  __shared__ u16 Vs[2][64*72];   // [dim][token]
  __shared__ u16 Ps[4][16*72];   // per-wave P round-trip (intra-wave only)
  const u16* qb = q_r + (size_t)bh*S*64;
  const u16* kb = k_r + (size_t)bh*S*64;
  const u16* vb = v_t + (size_t)bh*64*S;
  int rr = t>>2, p16 = (t&3)*16;          // staging coords: row 0..63, 16 elems
  #pragma unroll
  for (int ti=0; ti<2; ti++){
    int qt = ti ? (31-pr) : pr;
    int q0 = qt*64;
    bf16x8 qf0 = *(const bf16x8*)(qb + (size_t)(q0 + w*16 + ln)*64 + lg*8);
    bf16x8 qf1 = *(const bf16x8*)(qb + (size_t)(q0 + w*16 + ln)*64 + 32 + lg*8);
    f32x4 oacc[4] = {};
    float mi_[4], li_[4];
    #pragma unroll
    for (int r=0;r<4;r++){ mi_[r]=-1e30f; li_[r]=0.f; }
    // stage tile kv=0 into buffer 0
    __syncthreads();   // protect LDS from previous q-tile's reads
    {
      *(bf16x8*)&Ks[0][rr*72+p16]   = *(const bf16x8*)(kb + (size_t)rr*64 + p16);
      *(bf16x8*)&Ks[0][rr*72+p16+8] = *(const bf16x8*)(kb + (size_t)rr*64 + p16 + 8);
      *(bf16x8*)&Vs[0][rr*72+p16]   = *(const bf16x8*)(vb + (size_t)rr*S + p16);
      *(bf16x8*)&Vs[0][rr*72+p16+8] = *(const bf16x8*)(vb + (size_t)rr*S + p16 + 8);
    }
    __syncthreads();
    for (int kv=0; kv<=qt; kv++){
      int cur = kv&1;
      int k0 = kv*64;
      bool hasnext = kv < qt;
      bf16x8 nk0, nk1, nv0, nv1;
      if (hasnext){                 // issue next tile's global loads early
        int kn = k0 + 64;
        nk0 = *(const bf16x8*)(kb + (size_t)(kn+rr)*64 + p16);
        nk1 = *(const bf16x8*)(kb + (size_t)(kn+rr)*64 + p16 + 8);
        nv0 = *(const bf16x8*)(vb + (size_t)rr*S + kn + p16);
        nv1 = *(const bf16x8*)(vb + (size_t)rr*S + kn + p16 + 8);
      }
      // S = q K^T  (values already in log2 units)
      f32x4 sv[4];
      #pragma unroll
      for (int ni=0;ni<4;ni++){
        bf16x8 kf0 = *(const bf16x8*)&Ks[cur][(ni*16+ln)*72 + lg*8];
        bf16x8 kf1 = *(const bf16x8*)&Ks[cur][(ni*16+ln)*72 + 32 + lg*8];
        f32x4 z = {};
        z = __builtin_amdgcn_mfma_f32_16x16x32_bf16(qf0, kf0, z, 0,0,0);
        z = __builtin_amdgcn_mfma_f32_16x16x32_bf16(qf1, kf1, z, 0,0,0);
        sv[ni] = z;
      }
      bool diag = (kv==qt);
      float pm[4][4], alpha[4];
      #pragma unroll
      for (int r=0;r<4;r++){
        int qrow = q0 + w*16 + lg*4 + r;
        float rm = -1e30f;
        #pragma unroll
        for (int ni=0;ni<4;ni++){
          float xs = sv[ni][r];
          if (diag && (k0+ni*16+ln) > qrow) xs = -1e30f;
          sv[ni][r] = xs;
          rm = fmaxf(rm, xs);
        }
        #pragma unroll
        for (int m=1;m<16;m<<=1) rm = fmaxf(rm, __shfl_xor(rm,m,64));
        float mn = fmaxf(mi_[r], rm);
        alpha[r] = exp2f(mi_[r] - mn);
        float ls = 0.f;
        #pragma unroll
        for (int ni=0;ni<4;ni++){ float pp = exp2f(sv[ni][r]-mn); pm[ni][r]=pp; ls+=pp; }
        #pragma unroll
        for (int m=1;m<16;m<<=1) ls += __shfl_xor(ls,m,64);
        li_[r] = li_[r]*alpha[r] + ls;
        mi_[r] = mn;
      }
      // C-layout -> A-layout round trip through per-wave LDS: no block barrier needed
      // (intra-wave DS ops are in-order); compiler barriers pin source order vs TBAA.
      asm volatile("" ::: "memory");
      #pragma unroll
      for (int ni=0;ni<4;ni++)
        #pragma unroll
        for (int r=0;r<4;r++)
          Ps[w][(lg*4+r)*72 + ni*16 + ln] = f2b(pm[ni][r]);
      asm volatile("" ::: "memory");
      bf16x8 pf0 = *(const bf16x8*)&Ps[w][ln*72 + lg*8];
      bf16x8 pf1 = *(const bf16x8*)&Ps[w][ln*72 + 32 + lg*8];
      #pragma unroll
      for (int dt=0; dt<4; dt++){
        bf16x8 vf0 = *(const bf16x8*)&Vs[cur][(dt*16+ln)*72 + lg*8];
        bf16x8 vf1 = *(const bf16x8*)&Vs[cur][(dt*16+ln)*72 + 32 + lg*8];
        f32x4 oo = oacc[dt];
        #pragma unroll
        for (int r=0;r<4;r++) oo[r] *= alpha[r];
        oo = __builtin_amdgcn_mfma_f32_16x16x32_bf16(pf0, vf0, oo, 0,0,0);
        oo = __builtin_amdgcn_mfma_f32_16x16x32_bf16(pf1, vf1, oo, 0,0,0);
        oacc[dt] = oo;
      }
      if (hasnext){
        int nb = cur^1;
        *(bf16x8*)&Ks[nb][rr*72+p16]   = nk0;
        *(bf16x8*)&Ks[nb][rr*72+p16+8] = nk1;
        *(bf16x8*)&Vs[nb][rr*72+p16]   = nv0;
        *(bf16x8*)&Vs[nb][rr*72+p16+8] = nv1;
      }
      __syncthreads();
    }
    #pragma unroll
    for (int dt=0; dt<4; dt++){
      #pragma unroll
      for (int r=0;r<4;r++){
        int tok = q0 + w*16 + lg*4 + r;
        int dim = dt*16 + ln;
        o[((size_t)(b*S+tok))*1024 + h*64 + dim] = f2b(oacc[dt][r] / li_[r]);
      }
    }
  }
}

// ---------------- SwiGLU: g = silu(a13[:, :4096]) * a13[:, 4096:]  (bf16) ----------------
__global__ __launch_bounds__(256) void silu_kernel(const u16* __restrict__ a13, u16* __restrict__ g){
  size_t idx = ((size_t)blockIdx.x*256 + threadIdx.x)*8;
  size_t r = idx >> 12;
  size_t c = idx & 4095;
  const u16* p1 = a13 + r*8192 + c;
  const u16* p3 = p1 + 4096;
  bf16x8 x1 = *(const bf16x8*)p1;
  bf16x8 x3 = *(const bf16x8*)p3;
  u16 outv[8];
  #pragma unroll
  for (int i=0;i<8;i++){
    float a = (float)x1[i], b3 = (float)x3[i];
    float s = a / (1.f + __expf(-a));
    outv[i] = f2b(s*b3);
  }
  uint4 ov;
  ov.x = (unsigned)outv[0] | ((unsigned)outv[1]<<16);
  ov.y = (unsigned)outv[2] | ((unsigned)outv[3]<<16);
  ov.z = (unsigned)outv[4] | ((unsigned)outv[5]<<16);
  ov.w = (unsigned)outv[6] | ((unsigned)outv[7]<<16);
  *(uint4*)(g + idx) = ov;
}

// ---------------- out = x (+ rw * (h + y) on selected rows), f32 out ----------------
__global__ __launch_bounds__(256) void final_kernel(const float* __restrict__ x, const float* __restrict__ h,
        const u16* __restrict__ y, const int* __restrict__ inv, const float* __restrict__ rw,
        float* __restrict__ out){
  int row = blockIdx.x;
  int b = row>>12;
  int t = threadIdx.x, d0 = t*4;
  float4 xv = *(const float4*)(x + (size_t)row*1024 + d0);
  float4* op = (float4*)(out + (size_t)row*1024 + d0);
  int j = inv[row];
  if (j < 0){ *op = xv; return; }
  int fr = b*2048 + j;
  float wgt = rw[fr];
  float4 hv = *(const float4*)(h + (size_t)fr*1024 + d0);
  uint2 yv = *(const uint2*)(y + (size_t)fr*1024 + d0);
  float y0=b2f((u16)(yv.x&0xffffu)), y1=b2f((u16)(yv.x>>16)), y2=b2f((u16)(yv.y&0xffffu)), y3=b2f((u16)(yv.y>>16));
  float4 ov;
  ov.x = xv.x + wgt*(hv.x + y0);
  ov.y = xv.y + wgt*(hv.y + y1);
  ov.z = xv.z + wgt*(hv.z + y2);
  ov.w = xv.w + wgt*(hv.w + y3);
  *op = ov;
}

extern "C" void kernel_launch(void* const* d_in, const int* in_sizes, int n_in,
                              void* d_out, int out_size, void* d_ws, size_t ws_size,
                              hipStream_t stream) {
  (void)in_sizes; (void)n_in; (void)out_size; (void)ws_size;
  const float* x     = (const float*)d_in[0];
  // d_in[1] = mask (tril, static) -- unused, causality computed by index
  const float* fcos  = (const float*)d_in[2];
  const float* fsin  = (const float*)d_in[3];
  const float* wr    = (const float*)d_in[4];
  const float* anorm = (const float*)d_in[5];
  const float* wq    = (const float*)d_in[6];
  const float* wk    = (const float*)d_in[7];
  const float* wv    = (const float*)d_in[8];
  const float* wo    = (const float*)d_in[9];
  const float* fnorm = (const float*)d_in[10];
  const float* w1    = (const float*)d_in[11];
  const float* w2    = (const float*)d_in[12];
  const float* w3    = (const float*)d_in[13];
  float* out = (float*)d_out;

  char* W = (char*)d_ws;
  const size_t MB = 1024*1024;
  u16* WqkvT = (u16*)(W + 0);          // 6 MB  (3072 x 1024 bf16)
  u16* WoT   = (u16*)(W + 6*MB);       // 2 MB
  u16* W13T  = (u16*)(W + 8*MB);       // 16 MB (8192 x 1024)
  u16* W2T   = (u16*)(W + 24*MB);      // 8 MB  (1024 x 4096)
  float* xf  = (float*)(W + 32*MB);    // 16 MB f32 gathered x (dead after o-proj)
  u16* xn    = (u16*)(W + 48*MB);      // 8 MB  (dead after QKV gemm)
  u16* QKV   = (u16*)(W + 56*MB);      // 24 MB (dead after rope)
  u16* q_r   = (u16*)(W + 80*MB);      // 8 MB  (dead after flash)
  u16* k_r   = (u16*)(W + 88*MB);      // 8 MB
  u16* v_r   = (u16*)(W + 96*MB);      // 8 MB  (dead after v-transpose)
  u16* v_t   = (u16*)(W + 104*MB);     // 8 MB  (dead after flash)
  u16* attno = (u16*)(W + 112*MB);     // 8 MB  (dead after o-proj)
  float* hbuf= (float*)(W + 120*MB);   // 16 MB f32 (live till final)
  u16* hn    = (u16*)(W + 136*MB);     // 8 MB  (dead after FFN13)
  u16* a13   = (u16*)(W + 48*MB);      // 64 MB overlay (48..112MB, all dead by then)
  u16* g     = (u16*)(W + 144*MB);     // 32 MB
  u16* ybuf  = (u16*)(W + 32*MB);      // 8 MB overlay on dead xf
  float* logits = (float*)(W + 176*MB);            // 32 KB
  int*   sel    = (int*)(W + 176*MB + 64*1024);    // 16 KB
  float* rw     = (float*)(W + 176*MB + 96*1024);  // 16 KB
  int*   inv    = (int*)(W + 176*MB + 128*1024);   // 32 KB

  dim3 tb(32,8);
  // weight transposes + f32->bf16 (Bt layout for gemm_bt)
  transpose_f2b<<<dim3(32,32,1),  tb, 0, stream>>>(wq, WqkvT,                1024, 1024);
  transpose_f2b<<<dim3(32,32,1),  tb, 0, stream>>>(wk, WqkvT + 1024*1024,    1024, 1024);
  transpose_f2b<<<dim3(32,32,1),  tb, 0, stream>>>(wv, WqkvT + 2*1024*1024,  1024, 1024);
  transpose_f2b<<<dim3(32,32,1),  tb, 0, stream>>>(wo, WoT,                  1024, 1024);
  transpose_f2b<<<dim3(128,32,1), tb, 0, stream>>>(w1, W13T,                 1024, 4096);
  transpose_f2b<<<dim3(128,32,1), tb, 0, stream>>>(w3, W13T + 4096*1024,     1024, 4096);
  transpose_f2b<<<dim3(32,128,1), tb, 0, stream>>>(w2, W2T,                  4096, 1024);

  router_kernel<<<2048, 256, 0, stream>>>(x, wr, logits);
  topk_kernel<<<2, 1024, 0, stream>>>(logits, sel, rw, inv);
  rmsnorm_kernel<<<4096, 256, 0, stream>>>(x, anorm, sel, xn, xf);
  gemm_bt<128,u16><<<dim3(24,32), 256, 0, stream>>>(xn, WqkvT, QKV, nullptr, 4096, 3072, 1024);
  rope_kernel<<<4096, 256, 0, stream>>>(QKV, fcos, fsin, q_r, k_r, v_r);
  transpose_bf16<<<dim3(2,64,32), tb, 0, stream>>>(v_r, v_t, 2048, 64);
  flash_kernel<<<dim3(16,32), 256, 0, stream>>>(q_r, k_r, v_t, attno);
  gemm_bt<64,float><<<dim3(16,32), 256, 0, stream>>>(attno, WoT, hbuf, xf, 4096, 1024, 1024);
  rmsnorm_kernel<<<4096, 256, 0, stream>>>(hbuf, fnorm, nullptr, hn, nullptr);
  gemm_bt<128,u16><<<dim3(64,32), 256, 0, stream>>>(hn, W13T, a13, nullptr, 4096, 8192, 1024);
  silu_kernel<<<8192, 256, 0, stream>>>(a13, g);
  gemm_bt<64,u16><<<dim3(16,32), 256, 0, stream>>>(g, W2T, ybuf, nullptr, 4096, 1024, 4096);
  final_kernel<<<8192, 256, 0, stream>>>(x, hbuf, ybuf, inv, rw, out);
}